// Round 12
// baseline (284.121 us; speedup 1.0000x reference)
//
#include <hip/hip_runtime.h>
#include <hip/hip_bf16.h>
#include <stdint.h>

typedef __attribute__((ext_vector_type(8))) __bf16 bf16x8;
typedef __attribute__((ext_vector_type(4))) float f32x4;

#define BM 256
#define BN 256
#define BKT 32              // K per ring slot
#define SLOT 16384          // 256 rows x 32 k x 2B
// ring-4 slots = 128 KiB LDS; stage lead 3 tiles

// ---------------- NVFP4 quantize-dequantize (factored: no global scale) ----------------

__device__ __forceinline__ float fp8_e4m3_rne(float x) {
  if (x < 0.015625f) {
    return rintf(x * 512.0f) * 0.001953125f;
  }
  uint32_t u = __float_as_uint(x);
  uint32_t keep = u & 0xFFF00000u;
  uint32_t rem  = u & 0x000FFFFFu;
  uint32_t lsb  = (u >> 20) & 1u;
  if (rem > 0x80000u || (rem == 0x80000u && lsb)) keep += 0x100000u;
  return __uint_as_float(keep);
}

__device__ __forceinline__ float snap_lvl(float a) {
  if (a > 5.0f)  return 6.0f;
  if (a > 3.5f)  return 4.0f;
  if (a > 2.5f)  return 3.0f;
  if (a > 1.75f) return 2.0f;
  if (a > 1.25f) return 1.5f;
  if (a > 0.75f) return 1.0f;
  if (a > 0.25f) return 0.5f;
  return 0.0f;
}

// fused: blocks [0, nblkA) quantize x -> Aq; [nblkA, nblkA+nblkB) quantize w -> Bq
__global__ __launch_bounds__(256) void quant_nvfp4_fused(
    const float* __restrict__ inA, unsigned short* __restrict__ outA,
    const float* __restrict__ gsA,
    const float* __restrict__ inB, unsigned short* __restrict__ outB,
    const float* __restrict__ gsB, int nblkA, int nblkTot) {
  int b = blockIdx.x * 256 + threadIdx.x;
  if (b >= nblkTot) return;
  const float* in; unsigned short* out; float gs;
  if (b < nblkA) { in = inA + (size_t)b * 16; out = outA + (size_t)b * 16; gs = gsA[0]; }
  else { int b2 = b - nblkA; in = inB + (size_t)b2 * 16; out = outB + (size_t)b2 * 16; gs = gsB[0]; }
  float v[16];
#pragma unroll
  for (int i = 0; i < 4; ++i) {
    float4 t4 = reinterpret_cast<const float4*>(in)[i];
    v[i * 4 + 0] = t4.x; v[i * 4 + 1] = t4.y;
    v[i * 4 + 2] = t4.z; v[i * 4 + 3] = t4.w;
  }
  float amax = 0.0f;
#pragma unroll
  for (int i = 0; i < 16; ++i) amax = fmaxf(amax, fabsf(v[i]));
  float bs8 = fp8_e4m3_rne(amax / (6.0f * gs));
  float scale = fmaxf(bs8 * gs, 1e-12f);
  unsigned short o[16];
#pragma unroll
  for (int i = 0; i < 16; ++i) {
    float q = v[i] / scale;
    float a = fminf(fabsf(q), 6.0f);
    float val = copysignf(snap_lvl(a) * bs8, q);
    o[i] = (unsigned short)(__float_as_uint(val) >> 16);
  }
  uint4 w0 = make_uint4((uint32_t)o[0] | ((uint32_t)o[1] << 16),
                        (uint32_t)o[2] | ((uint32_t)o[3] << 16),
                        (uint32_t)o[4] | ((uint32_t)o[5] << 16),
                        (uint32_t)o[6] | ((uint32_t)o[7] << 16));
  uint4 w1 = make_uint4((uint32_t)o[8]  | ((uint32_t)o[9]  << 16),
                        (uint32_t)o[10] | ((uint32_t)o[11] << 16),
                        (uint32_t)o[12] | ((uint32_t)o[13] << 16),
                        (uint32_t)o[14] | ((uint32_t)o[15] << 16));
  uint4* op = reinterpret_cast<uint4*>(out);
  op[0] = w0;
  op[1] = w1;
}

// ---------------- bf16 GEMM, C = A * B^T ; m201 skeleton + plain C++ loads ----------------

__device__ __forceinline__ void async_lds16(const void* g, void* l) {
  __builtin_amdgcn_global_load_lds((__attribute__((address_space(1))) void*)(g),
                                   (__attribute__((address_space(3))) void*)(l),
                                   16, 0, 0);
}

#define VMC(S) asm volatile("s_waitcnt vmcnt(" S ")" ::: "memory")

#define LDB(ni, SOFF) (*(const bf16x8*)((const char*)Bs + offB[ni] + (SOFF)))
#define LDA(mi, SOFF) (*(const bf16x8*)((const char*)As + offA[mi] + (SOFF)))

#define MFMA_ROW(mi, av) do {                                                  \
    acc[mi][0] = __builtin_amdgcn_mfma_f32_16x16x32_bf16(av, b0f, acc[mi][0], 0, 0, 0); \
    acc[mi][1] = __builtin_amdgcn_mfma_f32_16x16x32_bf16(av, b1f, acc[mi][1], 0, 0, 0); \
    acc[mi][2] = __builtin_amdgcn_mfma_f32_16x16x32_bf16(av, b2f, acc[mi][2], 0, 0, 0); \
    acc[mi][3] = __builtin_amdgcn_mfma_f32_16x16x32_bf16(av, b3f, acc[mi][3], 0, 0, 0); \
  } while (0)

// Phase 1 of tile (slot SOFF): 8 plain ds-loads (B all + A-lo), stage A(T+3),
// barrier, lgkm(0), setprio, 16 MFMA (mi 0-3), setprio, barrier.
#define PH1(SOFF, STG) do {                                                    \
    b0f = LDB(0, SOFF); b1f = LDB(1, SOFF);                                    \
    b2f = LDB(2, SOFF); b3f = LDB(3, SOFF);                                    \
    bf16x8 a0f = LDA(0, SOFF), a1f = LDA(1, SOFF);                             \
    bf16x8 a2f = LDA(2, SOFF), a3f = LDA(3, SOFF);                             \
    STG;                                                                       \
    __builtin_amdgcn_s_barrier();                                              \
    asm volatile("s_waitcnt lgkmcnt(0)" ::: "memory");                         \
    __builtin_amdgcn_s_setprio(1);                                             \
    MFMA_ROW(0, a0f); MFMA_ROW(1, a1f); MFMA_ROW(2, a2f); MFMA_ROW(3, a3f);    \
    __builtin_amdgcn_s_setprio(0);                                             \
    __builtin_amdgcn_s_barrier();                                              \
  } while (0)

// Phase 2: 4 plain ds-loads (A-hi; B reused in regs), stage B(T+3), counted
// vmcnt gate, barrier, lgkm(0), setprio, 16 MFMA (mi 4-7), setprio, barrier.
#define PH2(SOFF, STG, VMS) do {                                               \
    bf16x8 a4f = LDA(4, SOFF), a5f = LDA(5, SOFF);                             \
    bf16x8 a6f = LDA(6, SOFF), a7f = LDA(7, SOFF);                             \
    STG;                                                                       \
    VMS;                                                                       \
    __builtin_amdgcn_s_barrier();                                              \
    asm volatile("s_waitcnt lgkmcnt(0)" ::: "memory");                         \
    __builtin_amdgcn_s_setprio(1);                                             \
    MFMA_ROW(4, a4f); MFMA_ROW(5, a5f); MFMA_ROW(6, a6f); MFMA_ROW(7, a7f);    \
    __builtin_amdgcn_s_setprio(0);                                             \
    __builtin_amdgcn_s_barrier();                                              \
  } while (0)

#define STG_A(TOFF, SO) do {                                                   \
    async_lds16(pA0 + (TOFF) * BKT, (char*)As + (SO) + lo0);                   \
    async_lds16(pA1 + (TOFF) * BKT, (char*)As + (SO) + lo1);                   \
  } while (0)
#define STG_B(TOFF, SO) do {                                                   \
    async_lds16(pB0 + (TOFF) * BKT, (char*)Bs + (SO) + lo0);                   \
    async_lds16(pB1 + (TOFF) * BKT, (char*)Bs + (SO) + lo1);                   \
  } while (0)

__global__ __launch_bounds__(512, 2) void gemm_bt_bf16(
    const unsigned short* __restrict__ A, const unsigned short* __restrict__ B,
    const float* __restrict__ bias, const float* __restrict__ gsx,
    const float* __restrict__ gsw, float* __restrict__ C,
    int M, int N, int K) {
  __shared__ __align__(16) unsigned short As[4 * 8192];   // 64 KiB
  __shared__ __align__(16) unsigned short Bs[4 * 8192];   // 64 KiB

  const int t = threadIdx.x;
  const int l = t & 63;
  const int w = t >> 6;
  const int wm = w >> 2, wn = w & 3;     // 2x4 waves; wave tile = 128(M) x 64(N)

  // bijective XCD swizzle (nwg = 512, divisible by 8)
  const int nbn = N / BN;
  const int nwg = (M / BM) * nbn;
  const int cpx = nwg >> 3;
  int bid = blockIdx.x;
  int logical = (bid & 7) * cpx + (bid >> 3);
  const int bm = logical / nbn, bn = logical % nbn;
  const int brow = bm * BM, bcol = bn * BN;

  // staging: linear LDS dest, inverse-swizzled global source (involution q^(((q>>7)&3)<<4))
  unsigned int b0 = (unsigned int)t * 16u;
  unsigned int b1 = b0 + 8192u;
  unsigned int bp0 = b0 ^ (((b0 >> 7) & 3u) << 4);
  unsigned int bp1 = b1 ^ (((b1 >> 7) & 3u) << 4);
  const unsigned int lo0 = b0, lo1 = b1;
  const unsigned short* pA0 = A + (size_t)(brow + (bp0 >> 6)) * K + ((bp0 & 63u) >> 1);
  const unsigned short* pA1 = A + (size_t)(brow + (bp1 >> 6)) * K + ((bp1 & 63u) >> 1);
  const unsigned short* pB0 = B + (size_t)(bcol + (bp0 >> 6)) * K + ((bp0 & 63u) >> 1);
  const unsigned short* pB1 = B + (size_t)(bcol + (bp1 >> 6)) * K + ((bp1 & 63u) >> 1);

  // swizzled fragment read byte-offsets (within a slot)
  unsigned int offA[8], offB[4];
#pragma unroll
  for (int mi = 0; mi < 8; ++mi) {
    unsigned int r = wm * 128 + mi * 16 + (l & 15);
    unsigned int q = r * 64 + ((l >> 4) << 4);
    offA[mi] = q ^ (((q >> 7) & 3u) << 4);
  }
#pragma unroll
  for (int ni = 0; ni < 4; ++ni) {
    unsigned int r = wn * 64 + ni * 16 + (l & 15);
    unsigned int q = r * 64 + ((l >> 4) << 4);
    offB[ni] = q ^ (((q >> 7) & 3u) << 4);
  }

  f32x4 acc[8][4] = {};
  bf16x8 b0f, b1f, b2f, b3f;

  // prologue: stage tiles 0,1,2 -> slots 0,1,2; confirm tile 0 (8 newest in flight)
  STG_A(0, 0);        STG_B(0, 0);
  STG_A(1, SLOT);     STG_B(1, SLOT);
  STG_A(2, 2 * SLOT); STG_B(2, 2 * SLOT);
  VMC("8");
  __builtin_amdgcn_s_barrier();

  // steady: 31 iterations x 4 tiles (T = 0..123); tile Tb+j reads slot j,
  // stages tile Tb+j+3 -> slot (j+3)&3. Gate at PH2: vmcnt(8) confirms tile T+1
  // (newer = stages of T+2, T+3 = 8 exactly). WAR: slot (j+3)&3 was last read
  // at tile T-1, drained by lgkm(0) before that tile's closing barrier.
#pragma unroll 1
  for (int it = 0; it < 31; ++it) {
    PH1(0,        STG_A(3, 3 * SLOT));
    PH2(0,        STG_B(3, 3 * SLOT), VMC("8"));
    PH1(SLOT,     STG_A(4, 0));
    PH2(SLOT,     STG_B(4, 0), VMC("8"));
    PH1(2 * SLOT, STG_A(5, SLOT));
    PH2(2 * SLOT, STG_B(5, SLOT), VMC("8"));
    PH1(3 * SLOT, STG_A(6, 2 * SLOT));
    PH2(3 * SLOT, STG_B(6, 2 * SLOT), VMC("8"));
    pA0 += 4 * BKT; pA1 += 4 * BKT; pB0 += 4 * BKT; pB1 += 4 * BKT;
  }
  // tail: T=124 (slot 0, stages 127 -> slot 3), 125, 126, 127
  PH1(0,        STG_A(3, 3 * SLOT));
  PH2(0,        STG_B(3, 3 * SLOT), VMC("8"));
  PH1(SLOT,     );
  PH2(SLOT,     , VMC("4"));
  PH1(2 * SLOT, );
  PH2(2 * SLOT, , VMC("0"));
  PH1(3 * SLOT, );
  PH2(3 * SLOT, , );

  // ---- epilogue ----
  const float gscale = gsx[0] * gsw[0];
  float bias_r[4];
#pragma unroll
  for (int ni = 0; ni < 4; ++ni)
    bias_r[ni] = bias[bcol + wn * 64 + ni * 16 + (l & 15)];
#pragma unroll
  for (int mi = 0; mi < 8; ++mi) {
#pragma unroll
    for (int ni = 0; ni < 4; ++ni) {
#pragma unroll
      for (int r = 0; r < 4; ++r) {
        int row = brow + wm * 128 + mi * 16 + (l >> 4) * 4 + r;
        int col = bcol + wn * 64 + ni * 16 + (l & 15);
        C[(size_t)row * N + col] = acc[mi][ni][r] * gscale + bias_r[ni];
      }
    }
  }
}

// ---------------- launch ----------------

extern "C" void kernel_launch(void* const* d_in, const int* in_sizes, int n_in,
                              void* d_out, int out_size, void* d_ws, size_t ws_size,
                              hipStream_t stream) {
  const float* x    = (const float*)d_in[0];
  const float* wgt  = (const float*)d_in[1];
  const float* bias = (const float*)d_in[2];
  const float* isc  = (const float*)d_in[3];
  const float* wsc  = (const float*)d_in[4];
  float* out = (float*)d_out;

  const int N = in_sizes[2];            // 4096
  const int K = in_sizes[1] / N;        // 4096
  const int M = in_sizes[0] / K;        // 8192

  unsigned short* Aq = (unsigned short*)d_ws;
  unsigned short* Bq = Aq + (size_t)M * K;

  int nblkA = M * K / 16;
  int nblkB = N * K / 16;
  int nblkTot = nblkA + nblkB;
  quant_nvfp4_fused<<<(nblkTot + 255) / 256, 256, 0, stream>>>(
      x, Aq, isc, wgt, Bq, wsc, nblkA, nblkTot);

  dim3 grid((M / BM) * (N / BN));
  gemm_bt_bf16<<<grid, 512, 0, stream>>>(Aq, Bq, bias, isc, wsc, out, M, N, K);
}